// Round 1
// baseline (79.877 us; speedup 1.0000x reference)
//
#include <hip/hip_runtime.h>
#include <math.h>

#define BB   8
#define IND  128
#define OUTD 128
#define NN   256
#define NQ   64          // NN/4 float4 quads
#define BN_EPS 1e-5f

// ---------------- Fully fused kernel: proj + Y + ReLU + BN + affine --------
// Grid = 128 (one block per channel c), block = (64, 8) = 8 waves.
// Wave w handles batch b=w across all of n (lane = n-quad), identical inner
// loop to the previous k1 (bit-identical accumulation order). BN's (B, n)
// reduction is completed inside the block via 64 B of LDS — no workspace,
// no second kernel, no pbuf round-trip. Output written once, coalesced.
__global__ __launch_bounds__(512) void k_fused(
    const float* __restrict__ A,     // [B, IND, NN]
    const float* __restrict__ P1,    // [OUTD, IND]
    const float* __restrict__ P2,    // [OUTD, IND]
    const float* __restrict__ kw,    // [OUTD, IND]
    const float* __restrict__ gamma, // [OUTD]
    const float* __restrict__ beta,  // [OUTD]
    float* __restrict__ out)         // [B, OUTD, NN]
{
    const int c = blockIdx.x;
    const int b = threadIdx.y;      // 0..7 = batch, one wave each
    const int x = threadIdx.x;      // lane 0..63 = n-quad

    const float4* __restrict__ A4 = (const float4*)A + (size_t)b * IND * NQ;
    const float* __restrict__ w1 = P1 + c * IND;
    const float* __restrict__ w2 = P2 + c * IND;
    const float* __restrict__ w3 = kw + c * IND;

    float a1[4] = {0.f, 0.f, 0.f, 0.f};
    float vv[4] = {0.f, 0.f, 0.f, 0.f};
    float kv[4] = {0.f, 0.f, 0.f, 0.f};

    #pragma unroll
    for (int blk = 0; blk < 16; ++blk) {
        float4 cur[8];
        #pragma unroll
        for (int j = 0; j < 8; ++j)
            cur[j] = A4[(blk * 8 + j) * NQ + x];     // 8 loads in flight
        #pragma unroll
        for (int j = 0; j < 8; ++j) {
            const int i = blk * 8 + j;
            const float wa = w1[i], wb = w2[i], wc = w3[i];  // uniform -> SGPR
            a1[0] = fmaf(wa, cur[j].x, a1[0]); a1[1] = fmaf(wa, cur[j].y, a1[1]);
            a1[2] = fmaf(wa, cur[j].z, a1[2]); a1[3] = fmaf(wa, cur[j].w, a1[3]);
            vv[0] = fmaf(wb, cur[j].x, vv[0]); vv[1] = fmaf(wb, cur[j].y, vv[1]);
            vv[2] = fmaf(wb, cur[j].z, vv[2]); vv[3] = fmaf(wb, cur[j].w, vv[3]);
            kv[0] = fmaf(wc, cur[j].x, kv[0]); kv[1] = fmaf(wc, cur[j].y, kv[1]);
            kv[2] = fmaf(wc, cur[j].z, kv[2]); kv[3] = fmaf(wc, cur[j].w, kv[3]);
        }
    }

    // S2 = sum_n kv^2, SV = sum_n |kv|*vv : full-n reduction within the wave.
    float s2 = 0.f, sv = 0.f;
    #pragma unroll
    for (int j = 0; j < 4; ++j) {
        s2 = fmaf(kv[j], kv[j], s2);
        sv = fmaf(fabsf(kv[j]), vv[j], sv);
    }
    #pragma unroll
    for (int off = 32; off >= 1; off >>= 1) {
        s2 += __shfl_xor(s2, off, 64);
        sv += __shfl_xor(sv, off, 64);
    }
    const float y = sv / sqrtf(s2);   // Y independent of i; Q cancels entirely.

    float p[4];
    float bnsum = 0.f, bnsq = 0.f;
    #pragma unroll
    for (int j = 0; j < 4; ++j) {
        float t = a1[j] + vv[j] + 0.1f * y;
        t = fmaxf(t, 0.f);            // ReLU
        p[j] = t;
        bnsum += t;
        bnsq  = fmaf(t, t, bnsq);
    }
    #pragma unroll
    for (int off = 32; off >= 1; off >>= 1) {
        bnsum += __shfl_xor(bnsum, off, 64);
        bnsq  += __shfl_xor(bnsq,  off, 64);
    }

    // BN partial combine across the 8 batch-waves, in-block via LDS.
    __shared__ float sred[2][BB];
    if (x == 0) {
        sred[0][b] = bnsum;
        sred[1][b] = bnsq;
    }
    __syncthreads();

    float tsum = 0.f, tsq = 0.f;
    #pragma unroll
    for (int w = 0; w < BB; ++w) {   // same order as old k2: w = 0..7
        tsum += sred[0][w];
        tsq  += sred[1][w];
    }
    const float inv   = 1.f / (float)(BB * NN);
    const float mean  = tsum * inv;
    const float var   = tsq * inv - mean * mean;     // biased var = jnp.var
    const float scale = gamma[c] * rsqrtf(var + BN_EPS);
    const float shift = beta[c] - mean * scale;

    float4* __restrict__ out4 = (float4*)out;
    out4[((size_t)b * OUTD + c) * NQ + x] =
        make_float4(fmaf(p[0], scale, shift), fmaf(p[1], scale, shift),
                    fmaf(p[2], scale, shift), fmaf(p[3], scale, shift));
}

extern "C" void kernel_launch(void* const* d_in, const int* in_sizes, int n_in,
                              void* d_out, int out_size, void* d_ws, size_t ws_size,
                              hipStream_t stream) {
    // setup_inputs order: A, P1, P2, q, k, gamma, beta, permutation_size1, BATCH_SIZE
    const float* A     = (const float*)d_in[0];
    const float* P1    = (const float*)d_in[1];
    const float* P2    = (const float*)d_in[2];
    // d_in[3] = q : unused (cancels in Alpha_norm)
    const float* kw    = (const float*)d_in[4];
    const float* gamma = (const float*)d_in[5];
    const float* beta  = (const float*)d_in[6];
    float* out = (float*)d_out;
    (void)d_ws; (void)ws_size;       // workspace unused: everything in-block

    dim3 blk(64, BB);
    k_fused<<<OUTD, blk, 0, stream>>>(A, P1, P2, kw, gamma, beta, out);
}